// Round 2
// 308.022 us; speedup vs baseline: 1.0015x; 1.0015x over previous
//
#include <hip/hip_runtime.h>

#define HW      16384
#define C_DIM   256
#define S_DIM   256
#define T_K     128
#define NH      8
#define DH      32
#define QKV_ST  768
#define B_DIM   2
#define SCALE_F 0.17677669529663687f
#define CAND    1536
#define EQCAP   512

typedef __attribute__((ext_vector_type(8))) short short8;
typedef __attribute__((ext_vector_type(4))) float f32x4;

// round-to-nearest-even float -> bf16 (as short)
__device__ __forceinline__ short f2bf(float f) {
    unsigned u = __float_as_uint(f);
    unsigned r = (u + 0x7FFFu + ((u >> 16) & 1u)) >> 16;
    return (short)r;
}
__device__ __forceinline__ float bf2f(short s) {
    unsigned u = ((unsigned)(unsigned short)s) << 16;
    return __uint_as_float(u);
}

// sortable key: larger key <=> larger float (no NaNs in inputs)
__device__ __forceinline__ unsigned sortkey(float f) {
    unsigned u = __float_as_uint(f);
    return (u & 0x80000000u) ? ~u : (u | 0x80000000u);
}
__device__ __forceinline__ float keyval(unsigned k) {
    return __uint_as_float((k & 0x80000000u) ? (k ^ 0x80000000u) : ~k);
}

// wave-aggregated histogram add: one LDS atomic per distinct bin per wave
__device__ __forceinline__ void agg_hist_add(unsigned* hist, unsigned bin) {
    int lane = threadIdx.x & 63;
    unsigned long long rem = ~0ull;
    while (true) {
        int leader = __ffsll((unsigned long long)rem) - 1;
        unsigned lbin = __shfl(bin, leader, 64);
        unsigned long long eq = __ballot(bin == lbin);
        if (lane == leader) atomicAdd(&hist[lbin], (unsigned)__popcll(eq & rem));
        rem &= ~eq;
        if (rem == 0ull) break;
    }
}

// ---------------------------------------------------------------------------
// Kernel 1: per-pixel LN stats; 4 threads per pixel (quarter-C partials).
// Grid: B*HW/64 blocks of 256.
__launch_bounds__(256)
__global__ void ln_stats_kernel(const float* __restrict__ x,
                                float* __restrict__ mu,
                                float* __restrict__ rsig) {
    int q = threadIdx.x >> 6;        // 0..3  (channel quarter)
    int l = threadIdx.x & 63;        // pixel within block
    int p = blockIdx.x * 64 + l;
    int b = p >> 14;
    int n = p & (HW - 1);
    const float* xb = x + (size_t)b * C_DIM * HW + n;
    float s = 0.f, ss = 0.f;
#pragma unroll 8
    for (int c = q * 64; c < q * 64 + 64; c++) {
        float v = xb[(size_t)c * HW];
        s += v; ss += v * v;
    }
    __shared__ float ps[4][64], pss[4][64];
    ps[q][l] = s; pss[q][l] = ss;
    __syncthreads();
    if (threadIdx.x < 64) {
        float S  = ps[0][l] + ps[1][l] + ps[2][l] + ps[3][l];
        float SS = pss[0][l] + pss[1][l] + pss[2][l] + pss[3][l];
        float m   = S * (1.f / C_DIM);
        float var = fmaxf(SS * (1.f / C_DIM) - m * m, 0.f);
        int pp = blockIdx.x * 64 + l;
        mu[pp]   = m;
        rsig[pp] = rsqrtf(var + 1e-5f);
    }
}

// ---------------------------------------------------------------------------
// Kernel 1b: pack weights to bf16, layout Wb[o][c]
__global__ void wpack_kernel(const float* __restrict__ wq,
                             const float* __restrict__ wk,
                             const float* __restrict__ wv,
                             short* __restrict__ wb) {
    int gid  = blockIdx.x * 256 + threadIdx.x;
    int base = gid * 4;
    int o = base >> 8;
    int c = base & 255;
    const float* src = (o < 256) ? wq + (size_t)o * 256
                     : (o < 512) ? wk + (size_t)(o - 256) * 256
                                 : wv + (size_t)(o - 512) * 256;
    float4 w4 = *(const float4*)(src + c);
    short4 s4;
    s4.x = f2bf(w4.x); s4.y = f2bf(w4.y); s4.z = f2bf(w4.z); s4.w = f2bf(w4.w);
    *(short4*)&wb[base] = s4;
}

// ---------------------------------------------------------------------------
// Kernel 1c: LN-apply + transpose: xnT[b][n][c] = bf16(LN(x[b][c][n]))
__launch_bounds__(256)
__global__ void xpack_kernel(const float* __restrict__ x,
                             const float* __restrict__ g,
                             const float* __restrict__ beta,
                             const float* __restrict__ mu,
                             const float* __restrict__ rsig,
                             short* __restrict__ xnT) {
    int b  = blockIdx.z;
    int n0 = blockIdx.x * 64;
    int c0 = blockIdx.y * 64;
    int tid = threadIdx.x;

    __shared__ float t[64][65];

    {
        int cl = tid >> 2;
        int ni = (tid & 3) * 16;
        const float* src = x + ((size_t)b * C_DIM + c0 + cl) * HW + n0 + ni;
#pragma unroll
        for (int j = 0; j < 4; j++) {
            float4 v = *(const float4*)(src + j * 4);
            t[cl][ni + j * 4 + 0] = v.x;
            t[cl][ni + j * 4 + 1] = v.y;
            t[cl][ni + j * 4 + 2] = v.z;
            t[cl][ni + j * 4 + 3] = v.w;
        }
    }
    __syncthreads();

    {
        int nl = tid >> 2;
        int ci = (tid & 3) * 16;
        int n  = n0 + nl;
        float m  = mu[b * HW + n];
        float rs = rsig[b * HW + n];
        short8 s0, s1;
#pragma unroll
        for (int j = 0; j < 8; j++) {
            int c = c0 + ci + j;
            s0[j] = f2bf((t[ci + j][nl] - m) * rs * g[c] + beta[c]);
        }
#pragma unroll
        for (int j = 0; j < 8; j++) {
            int c = c0 + ci + 8 + j;
            s1[j] = f2bf((t[ci + 8 + j][nl] - m) * rs * g[c] + beta[c]);
        }
        short* dst = xnT + ((size_t)b * HW + n) * C_DIM + c0 + ci;
        *(short8*)(dst)     = s0;
        *(short8*)(dst + 8) = s1;
    }
}

// ---------------------------------------------------------------------------
// Kernel 2: bf16 MFMA QKV projection
#define E_STRIDE 136
__launch_bounds__(256)
__global__ void qkv_mfma_kernel(const short* __restrict__ xnT,
                                const short* __restrict__ wb,
                                short* __restrict__ qkv) {
    int b  = blockIdx.z;
    int n0 = blockIdx.x * 128;
    int o0 = blockIdx.y * 128;
    int tid  = threadIdx.x;
    int wv   = tid >> 6;
    int wn   = wv & 1;
    int wo   = wv >> 1;
    int lane = tid & 63;
    int quad = lane >> 4;
    int ln   = lane & 15;

    __shared__ __align__(16) short Es[128 * E_STRIDE];

    const short* arow[4];
    const short* brow[4];
#pragma unroll
    for (int mt = 0; mt < 4; mt++)
        arow[mt] = xnT + ((size_t)b * HW + n0 + wn * 64 + mt * 16 + ln) * C_DIM + quad * 8;
#pragma unroll
    for (int nt = 0; nt < 4; nt++)
        brow[nt] = wb + (size_t)(o0 + wo * 64 + nt * 16 + ln) * C_DIM + quad * 8;

    f32x4 acc[4][4];
    const f32x4 zero4 = {0.f, 0.f, 0.f, 0.f};
#pragma unroll
    for (int mt = 0; mt < 4; mt++)
#pragma unroll
        for (int nt = 0; nt < 4; nt++) acc[mt][nt] = zero4;

#pragma unroll 2
    for (int c0 = 0; c0 < C_DIM; c0 += 32) {
        short8 af[4], bf[4];
#pragma unroll
        for (int mt = 0; mt < 4; mt++) af[mt] = *(const short8*)(arow[mt] + c0);
#pragma unroll
        for (int nt = 0; nt < 4; nt++) bf[nt] = *(const short8*)(brow[nt] + c0);
#pragma unroll
        for (int mt = 0; mt < 4; mt++)
#pragma unroll
            for (int nt = 0; nt < 4; nt++)
                acc[mt][nt] = __builtin_amdgcn_mfma_f32_16x16x32_bf16(af[mt], bf[nt], acc[mt][nt], 0, 0, 0);
    }

#pragma unroll
    for (int mt = 0; mt < 4; mt++)
#pragma unroll
        for (int nt = 0; nt < 4; nt++)
#pragma unroll
            for (int r = 0; r < 4; r++)
                Es[(wn * 64 + mt * 16 + quad * 4 + r) * E_STRIDE + wo * 64 + nt * 16 + ln] =
                    f2bf(acc[mt][nt][r]);
    __syncthreads();

    {
        int nl   = tid >> 1;
        int half = tid & 1;
        const short* srcr = &Es[nl * E_STRIDE + half * 64];
        short* dst = qkv + ((size_t)b * HW + n0 + nl) * QKV_ST + o0 + half * 64;
#pragma unroll
        for (int j = 0; j < 8; j++)
            *(short8*)(dst + j * 8) = *(const short8*)(srcr + j * 8);
    }
}

// ---------------------------------------------------------------------------
// Kernel 3: exact top-128 per (b,s) row. 1024 threads.
// Race-free selection: uniform-register kneed/prefix; unique-writer s_sel.
__launch_bounds__(1024)
__global__ void topk_kernel(const float* __restrict__ aff,
                            float* __restrict__ sims,
                            int* __restrict__ idx) {
    int s = blockIdx.x, b = blockIdx.y;
    int tid = threadIdx.x;
    const float4* rowv4 = (const float4*)(aff + ((size_t)b * S_DIM + s) * HW);

    __shared__ unsigned hist[256];
    __shared__ unsigned sufs[256];
    __shared__ unsigned ckey[CAND];
    __shared__ int      cidx[CAND];
    __shared__ int      eqix[EQCAP];
    __shared__ int s_sel, cHi, cCand, cEq;

    if (tid == 0) { cHi = 0; cCand = 0; cEq = 0; }
    if (tid < 256) hist[tid] = 0;
    __syncthreads();

    // ---- pass 1: MSB-byte histogram over full row (wave-aggregated) ----
    for (int i = tid; i < HW / 4; i += 1024) {
        float4 v = rowv4[i];
        agg_hist_add(hist, sortkey(v.x) >> 24);
        agg_hist_add(hist, sortkey(v.y) >> 24);
        agg_hist_add(hist, sortkey(v.z) >> 24);
        agg_hist_add(hist, sortkey(v.w) >> 24);
    }
    __syncthreads();

    // ---- suffix scan (256 lanes active; barriers unconditional) ----
    if (tid < 256) sufs[tid] = hist[tid];
    __syncthreads();
#pragma unroll
    for (int off = 1; off < 256; off <<= 1) {
        unsigned v = 0;
        if (tid < 256 && tid + off < 256) v = sufs[tid + off];
        __syncthreads();
        if (tid < 256) sufs[tid] += v;
        __syncthreads();
    }

    int kneed = T_K;            // uniform register on every thread
    if (tid < 256) {
        unsigned above = (tid < 255) ? sufs[tid + 1] : 0u;
        if ((int)sufs[tid] >= kneed && (int)above < kneed) s_sel = tid;  // unique winner
    }
    __syncthreads();
    int sel = s_sel;            // uniform
    unsigned prefix = (unsigned)sel << 24;
    kneed -= (int)((sel < 255) ? sufs[sel + 1] : 0u);
    __syncthreads();

    float* so = sims + ((size_t)b * S_DIM + s) * T_K;
    int*   io = idx  + ((size_t)b * S_DIM + s) * T_K;

    // ---- pass 2: direct-emit above-bin, compact in-bin candidates ----
    for (int i = tid; i < HW / 4; i += 1024) {
        float4 v = rowv4[i];
        float vf[4] = {v.x, v.y, v.z, v.w};
#pragma unroll
        for (int j = 0; j < 4; j++) {
            unsigned u  = sortkey(vf[j]);
            unsigned hb = u >> 24;
            if (hb > (unsigned)sel) {
                int p = atomicAdd(&cHi, 1);
                so[p] = vf[j]; io[p] = i * 4 + j;
            } else if (hb == (unsigned)sel) {
                int c = atomicAdd(&cCand, 1);
                if (c < CAND) { ckey[c] = u; cidx[c] = i * 4 + j; }
            }
        }
    }
    __syncthreads();
    int nc = min(cCand, CAND);

    // ---- 3 radix refinements over candidates ----
    for (int shift = 16; shift >= 0; shift -= 8) {
        if (tid < 256) hist[tid] = 0;
        __syncthreads();
        unsigned mask = 0xFFFFFFFFu << (shift + 8);
        for (int i = tid; i < nc; i += 1024) {
            unsigned u = ckey[i];
            if ((u & mask) == prefix) atomicAdd(&hist[(u >> shift) & 255], 1u);
        }
        __syncthreads();
        if (tid < 256) sufs[tid] = hist[tid];
        __syncthreads();
#pragma unroll
        for (int off = 1; off < 256; off <<= 1) {
            unsigned v = 0;
            if (tid < 256 && tid + off < 256) v = sufs[tid + off];
            __syncthreads();
            if (tid < 256) sufs[tid] += v;
            __syncthreads();
        }
        if (tid < 256) {
            unsigned above = (tid < 255) ? sufs[tid + 1] : 0u;
            if ((int)sufs[tid] >= kneed && (int)above < kneed) s_sel = tid;
        }
        __syncthreads();
        sel = s_sel;
        prefix |= (unsigned)sel << shift;
        kneed  -= (int)((sel < 255) ? sufs[sel + 1] : 0u);
        __syncthreads();
    }

    unsigned T = prefix;        // exact 128th-largest key
    int kneedF = kneed;         // # of equal-to-T entries to keep (>=1)

    // ---- emit >T; compact ==T for deterministic tie resolution ----
    for (int i = tid; i < nc; i += 1024) {
        unsigned u = ckey[i];
        if (u > T) {
            int p = atomicAdd(&cHi, 1);
            so[p] = keyval(u); io[p] = cidx[i];
        } else if (u == T) {
            int q = atomicAdd(&cEq, 1);
            if (q < EQCAP) eqix[q] = cidx[i];
        }
    }
    __syncthreads();
    int m = min(cEq, EQCAP);

    // keep the kneedF SMALLEST indices among equals (jax tie order)
    float tval = keyval(T);
    for (int i = tid; i < m; i += 1024) {
        int my = eqix[i];
        int rank = 0;
        for (int j = 0; j < m; j++) rank += (eqix[j] < my);
        if (rank < kneedF) { so[127 - rank] = tval; io[127 - rank] = my; }
    }
}

// ---------------------------------------------------------------------------
// Kernel 4: MFMA attention per (b, s, h); qkv is bf16. sims folded into P.
// R7.1 changes vs 308us baseline:
//  - K_lds and Ps union'd (K dead after QK^T): LDS 37.4 KB -> 26.4 KB
//    (VT_STRIDE 136 -> 132), occupancy cap 4 -> 6 blocks/CU.
//  - Ps is wave-private: dropped the 4 per-mt __syncthreads; one barrier
//    after softmax protects the K/P union transition.
//  - sim/l division hoisted per-(mt,r): 16 -> 8 divides/thread.
//  - s_setprio(1) around MFMA clusters.
//  - Epilogue: plain scalar atomicAdd (global_atomic_pk_add_f32 does not
//    assemble on gfx950).
#define K_STRIDE 40
#define VT_STRIDE 132
union KPu {
    short K[T_K * K_STRIDE];
    short P[4][16 * VT_STRIDE];
};
__launch_bounds__(256)
__global__ void attn_kernel(const short* __restrict__ qkv,
                            const float* __restrict__ sims,
                            const int* __restrict__ idx,
                            float* __restrict__ acc) {
    int s = blockIdx.x, h = blockIdx.y, b = blockIdx.z;
    int tid  = threadIdx.x;
    int wv   = tid >> 6;
    int lane = tid & 63;
    int quad = lane >> 4;
    int ln   = lane & 15;

    __shared__ __align__(16) KPu KP;
    __shared__ __align__(16) short Vt[DH * VT_STRIDE];
    __shared__ float sim_s[T_K];
    __shared__ int   idx_s[T_K];

    if (tid < T_K) {
        sim_s[tid] = sims[((size_t)b * S_DIM + s) * T_K + tid];
        idx_s[tid] = idx [((size_t)b * S_DIM + s) * T_K + tid];
    }
    __syncthreads();

    const short* qkvb = qkv + (size_t)b * HW * QKV_ST;
    int co = h * DH;

    {
        int r  = tid >> 1;
        int hh = tid & 1;
        const short* base = qkvb + (size_t)idx_s[r] * QKV_ST + co + hh * 16;
        short8 k0 = *(const short8*)(base + 256);
        short8 k1 = *(const short8*)(base + 256 + 8);
        *(short8*)&KP.K[r * K_STRIDE + hh * 16]     = k0;
        *(short8*)&KP.K[r * K_STRIDE + hh * 16 + 8] = k1;
        short8 v0 = *(const short8*)(base + 512);
        short8 v1 = *(const short8*)(base + 512 + 8);
#pragma unroll
        for (int i = 0; i < 8; i++) Vt[(hh * 16 + i) * VT_STRIDE + r]     = v0[i];
#pragma unroll
        for (int i = 0; i < 8; i++) Vt[(hh * 16 + 8 + i) * VT_STRIDE + r] = v1[i];
    }

    short8 aq[2];
#pragma unroll
    for (int mt = 0; mt < 2; mt++) {
        int t = wv * 32 + mt * 16 + ln;
        aq[mt] = *(const short8*)(qkvb + (size_t)idx_s[t] * QKV_ST + co + quad * 8);
    }
    __syncthreads();

    f32x4 S[2][8];
    const f32x4 zero4 = {0.f, 0.f, 0.f, 0.f};
    __builtin_amdgcn_s_setprio(1);
#pragma unroll
    for (int nt = 0; nt < 8; nt++) {
        short8 kf = *(const short8*)&KP.K[(nt * 16 + ln) * K_STRIDE + quad * 8];
        S[0][nt] = __builtin_amdgcn_mfma_f32_16x16x32_bf16(aq[0], kf, zero4, 0, 0, 0);
        S[1][nt] = __builtin_amdgcn_mfma_f32_16x16x32_bf16(aq[1], kf, zero4, 0, 0, 0);
    }
    __builtin_amdgcn_s_setprio(0);

    float lrow[2][4];
#pragma unroll
    for (int mt = 0; mt < 2; mt++) {
#pragma unroll
        for (int r = 0; r < 4; r++) {
            float mx = S[mt][0][r];
#pragma unroll
            for (int nt = 1; nt < 8; nt++) mx = fmaxf(mx, S[mt][nt][r]);
            mx = fmaxf(mx, __shfl_xor(mx, 1, 64));
            mx = fmaxf(mx, __shfl_xor(mx, 2, 64));
            mx = fmaxf(mx, __shfl_xor(mx, 4, 64));
            mx = fmaxf(mx, __shfl_xor(mx, 8, 64));
            float l = 0.f;
#pragma unroll
            for (int nt = 0; nt < 8; nt++) {
                float p = __expf((S[mt][nt][r] - mx) * SCALE_F);
                S[mt][nt][r] = p;
                l += p;
            }
            l += __shfl_xor(l, 1, 64);
            l += __shfl_xor(l, 2, 64);
            l += __shfl_xor(l, 4, 64);
            l += __shfl_xor(l, 8, 64);
            lrow[mt][r] = l;
        }
    }

    // One barrier: all waves done reading KP.K (QK^T) before any wave
    // writes KP.P. Everything below is wave-private (P slice) or read-only.
    __syncthreads();

    float* accb = acc + (size_t)b * HW * C_DIM + co;
#pragma unroll
    for (int mt = 0; mt < 2; mt++) {
        float w[4];
#pragma unroll
        for (int r = 0; r < 4; r++)
            w[r] = sim_s[wv * 32 + mt * 16 + quad * 4 + r] / lrow[mt][r];

#pragma unroll
        for (int nt = 0; nt < 8; nt++) {
            float su = sim_s[nt * 16 + ln];
#pragma unroll
            for (int r = 0; r < 4; r++)
                KP.P[wv][(quad * 4 + r) * VT_STRIDE + nt * 16 + ln] = f2bf(S[mt][nt][r] * su);
        }

        f32x4 O[2] = {zero4, zero4};
        __builtin_amdgcn_s_setprio(1);
#pragma unroll
        for (int kt = 0; kt < 4; kt++) {
            short8 pa = *(const short8*)&KP.P[wv][ln * VT_STRIDE + kt * 32 + quad * 8];
#pragma unroll
            for (int nt2 = 0; nt2 < 2; nt2++) {
                short8 vb = *(const short8*)&Vt[(nt2 * 16 + ln) * VT_STRIDE + kt * 32 + quad * 8];
                O[nt2] = __builtin_amdgcn_mfma_f32_16x16x32_bf16(pa, vb, O[nt2], 0, 0, 0);
            }
        }
        __builtin_amdgcn_s_setprio(0);

#pragma unroll
        for (int nt2 = 0; nt2 < 2; nt2++)
#pragma unroll
            for (int r = 0; r < 4; r++) {
                int t = wv * 32 + mt * 16 + quad * 4 + r;
                atomicAdd(accb + (size_t)idx_s[t] * C_DIM + nt2 * 16 + ln,
                          O[nt2][r] * w[r]);
            }
    }
}

// ---------------------------------------------------------------------------
// Kernel 5: out[b][c][n] = bf2f(v[b][n][c]) + acc[b][n][c]
__launch_bounds__(256)
__global__ void transpose_add_kernel(const short* __restrict__ qkv,
                                     const float* __restrict__ acc,
                                     float* __restrict__ out) {
    int b  = blockIdx.z;
    int n0 = blockIdx.x * 32;
    int c0 = blockIdx.y * 32;
    int x = threadIdx.x & 31;
    int y = threadIdx.x >> 5;

    __shared__ float t[32][33];
#pragma unroll
    for (int r = 0; r < 4; r++) {
        int n = n0 + y + 8 * r;
        size_t row = (size_t)b * HW + n;
        t[y + 8 * r][x] = bf2f(qkv[row * QKV_ST + 512 + c0 + x]) + acc[row * C_DIM + c0 + x];
    }
    __syncthreads();
#pragma unroll
    for (int r = 0; r < 4; r++) {
        int c = c0 + y + 8 * r;
        out[((size_t)b * C_DIM + c) * HW + n0 + x] = t[x][y + 8 * r];
    }
}

// ---------------------------------------------------------------------------
extern "C" void kernel_launch(void* const* d_in, const int* in_sizes, int n_in,
                              void* d_out, int out_size, void* d_ws, size_t ws_size,
                              hipStream_t stream) {
    const float* x    = (const float*)d_in[0];
    const float* aff  = (const float*)d_in[1];
    const float* g    = (const float*)d_in[2];
    const float* beta = (const float*)d_in[3];
    const float* wq   = (const float*)d_in[4];
    const float* wk   = (const float*)d_in[5];
    const float* wv   = (const float*)d_in[6];
    float* out = (float*)d_out;

    char* ws = (char*)d_ws;
    short* qkv  = (short*)ws;                                   ws += (size_t)B_DIM * HW * QKV_ST * 2;
    short* xnT  = (short*)ws;                                   ws += (size_t)B_DIM * HW * C_DIM * 2;
    short* wbuf = (short*)ws;                                   ws += (size_t)QKV_ST * C_DIM * 2;
    float* mu   = (float*)ws;                                   ws += (size_t)B_DIM * HW * 4;
    float* rsig = (float*)ws;                                   ws += (size_t)B_DIM * HW * 4;
    float* simsb= (float*)ws;                                   ws += (size_t)B_DIM * S_DIM * T_K * 4;
    int*   idxb = (int*)ws;                                     ws += (size_t)B_DIM * S_DIM * T_K * 4;
    float* acc  = (float*)ws;

    hipMemsetAsync(acc, 0, (size_t)B_DIM * HW * C_DIM * sizeof(float), stream);

    ln_stats_kernel<<<dim3(B_DIM * HW / 64), 256, 0, stream>>>(x, mu, rsig);
    wpack_kernel<<<dim3(QKV_ST * C_DIM / 4 / 256), 256, 0, stream>>>(wq, wk, wv, wbuf);
    xpack_kernel<<<dim3(HW / 64, C_DIM / 64, B_DIM), 256, 0, stream>>>(
        x, g, beta, mu, rsig, xnT);
    qkv_mfma_kernel<<<dim3(HW / 128, QKV_ST / 128, B_DIM), 256, 0, stream>>>(
        xnT, wbuf, qkv);
    topk_kernel<<<dim3(S_DIM, B_DIM), 1024, 0, stream>>>(aff, simsb, idxb);
    attn_kernel<<<dim3(S_DIM, NH, B_DIM), 256, 0, stream>>>(qkv, simsb, idxb, acc);
    transpose_add_kernel<<<dim3(HW / 32, C_DIM / 32, B_DIM), 256, 0, stream>>>(
        qkv, acc, out);
}